// Round 9
// baseline (314.854 us; speedup 1.0000x reference)
//
#include <hip/hip_runtime.h>
#include <stdint.h>
#include <math.h>

typedef unsigned int uint_t;

#define FEAT 2048
#define DSTRIDE 2052   // FEAT + HIDDEN
#define WARM 40
#define LCH 1
#define STEPS (WARM + LCH)
#define NN 8192
#define PXROWS 8       // rows per k_px block (1024 blocks)

__device__ __forceinline__ float sigm_f(float x) {
    return __builtin_amdgcn_rcpf(1.f + __expf(-x));
}
__device__ __forceinline__ float tanh_f(float x) {
    // 1 - 2/(e^2x + 1); rcp is ~1 ulp, fine at 1e-2 threshold
    return 1.f - 2.f * __builtin_amdgcn_rcpf(__expf(2.f * x) + 1.f);
}

// ---------------------------------------------------------------------------
// K1 (f32 inputs): px2[n][gq] = feat[n,:]·Wx[gq,:2048] + b[gq] + th[gq]
// v7 (R8 resubmission — R7 run died with "container failed twice" and no
// profile; kernel audited memory-safe: max W index 8203 < 8208 floats, feat
// and px2 in-bounds, no barriers/spin/builtins that could hang. Identical
// resubmit disambiguates infra flake vs kernel, mirroring R4->R5.)
// v7: NO LDS, NO BARRIERS. History: v4b (LDS, 2 barriers/chunk) = 40us with
// VALUBusy 28% — stall-dominated by the vmcnt(0)-before-s_barrier drains.
// v5 (hoist loads) drained at one barrier + VGPR 112 -> 52us. v6 (T14 reg
// prefetch) spilled ~320B/thread (WRITE_SIZE 512KB->80MB) -> 65us.
// Root cause analysis: the LDS staging protects L2 bandwidth, which is NOT
// scarce — W is 128KB L2-resident; direct per-lane loads cost 1024 blocks x
// 128KB = 128MB of L2 traffic ~ 3.7us aggregate at 34.5TB/s. Dropping LDS
// removes every sync point: the fully-unrolled loop lets the compiler keep
// feat (HBM/L3) and W (L2) loads in flight continuously — no s_barrier ever
// forces a vmcnt(0) drain. Occupancy: LDS 0, VGPR ~100 -> 4+ waves/SIMD.
// W addresses per lane are IDENTICAL to v4b's LDS image (wa = W[g] +
// q*DSTRIDE + ch*512 + lane*4, wb = +256), same FMA order -> px2
// bit-identical -> absmax unchanged.
// px2 = 512 KB at head of d_out (f32 rows 0..63), consumed by k_scan before
// k_out_main overwrites it.
// ---------------------------------------------------------------------------
__global__ __launch_bounds__(256) void k_px(
    const float* __restrict__ feat,
    const float* __restrict__ Wf, const float* __restrict__ Wi,
    const float* __restrict__ Wg, const float* __restrict__ Wo,
    const float* __restrict__ bfp, const float* __restrict__ bip,
    const float* __restrict__ bgp, const float* __restrict__ bop,
    const float* __restrict__ thf, const float* __restrict__ thi,
    const float* __restrict__ thg, const float* __restrict__ tho,
    float* __restrict__ px2)
{
    const int t = threadIdx.x;
    const int wave = t >> 6, lane = t & 63;
    const int rowBase = blockIdx.x * PXROWS;
    const float* Ws[4] = {Wf, Wi, Wg, Wo};

    float acc[2][16];
#pragma unroll
    for (int r = 0; r < 2; ++r)
#pragma unroll
        for (int i = 0; i < 16; ++i) acc[r][i] = 0.f;

#pragma unroll
    for (int ch = 0; ch < 4; ++ch) {
        float4 fa[2], fb[2];
#pragma unroll
        for (int rr = 0; rr < 2; ++rr) {
            const int n = rowBase + wave * 2 + rr;
            const float* fp = feat + (size_t)n * FEAT + ch * 512;
            fa[rr] = *(const float4*)(fp + lane * 4);
            fb[rr] = *(const float4*)(fp + 256 + lane * 4);
        }
#pragma unroll
        for (int gq = 0; gq < 16; ++gq) {
            const float* wp = Ws[gq >> 2] + (gq & 3) * DSTRIDE + ch * 512;
            const float4 wa = *(const float4*)(wp + lane * 4);
            const float4 wb = *(const float4*)(wp + 256 + lane * 4);
#pragma unroll
            for (int rr = 0; rr < 2; ++rr) {
                float a = acc[rr][gq];
                a = fmaf(fa[rr].x, wa.x, a); a = fmaf(fa[rr].y, wa.y, a);
                a = fmaf(fa[rr].z, wa.z, a); a = fmaf(fa[rr].w, wa.w, a);
                a = fmaf(fb[rr].x, wb.x, a); a = fmaf(fb[rr].y, wb.y, a);
                a = fmaf(fb[rr].z, wb.z, a); a = fmaf(fb[rr].w, wb.w, a);
                acc[rr][gq] = a;
            }
        }
    }

    float bth[16];
    {
        const float* bs[4] = {bfp, bip, bgp, bop};
        const float* ts[4] = {thf, thi, thg, tho};
#pragma unroll
        for (int g = 0; g < 4; ++g)
#pragma unroll
            for (int q = 0; q < 4; ++q)
                bth[g * 4 + q] = bs[g][q] + ts[g][q];
    }

#pragma unroll
    for (int rr = 0; rr < 2; ++rr) {
#pragma unroll
        for (int i = 0; i < 16; ++i) {
            float v = acc[rr][i];
#pragma unroll
            for (int m = 32; m > 0; m >>= 1) v += __shfl_xor(v, m, 64);
            acc[rr][i] = v + bth[i];
        }
        if (lane == 0) {
            const int n = rowBase + wave * 2 + rr;
            float* dst = px2 + (size_t)n * 16;
            *(float4*)(dst + 0)  = make_float4(acc[rr][0],  acc[rr][1],  acc[rr][2],  acc[rr][3]);
            *(float4*)(dst + 4)  = make_float4(acc[rr][4],  acc[rr][5],  acc[rr][6],  acc[rr][7]);
            *(float4*)(dst + 8)  = make_float4(acc[rr][8],  acc[rr][9],  acc[rr][10], acc[rr][11]);
            *(float4*)(dst + 12) = make_float4(acc[rr][12], acc[rr][13], acc[rr][14], acc[rr][15]);
        }
    }
}

// ---------------------------------------------------------------------------
// K2: per-row warmup replay. 8192 chunks of 1 row each; every thread replays
// the 40 preceding rows from (h,c)=(0,0) then emits its single row. 128
// blocks x 64 threads -> 128 CUs (R2 lesson: CUs, not waves/SIMD).
// Rows n<40 bit-exact via the n<0 no-update guard; adversarial warmup bound
// 0.84^40 ~ 9.4e-4 << 1.06e-2 threshold; absmax bit-identical across
// WARM 64->40 (transcendental-dominated).
// px2 prefetched one step ahead (state-independent addresses). px2 is
// L2-resident (512 KB).
// qlayer(z,th) = [c1c2c3, c0c1, c0c1c2, c0c1c2c3], c_w = cos(z_w + th_w)
// (theta pre-added by k_px). hout = LAST 128 KB of d_out (rows 8176..8191).
// ---------------------------------------------------------------------------
__global__ __launch_bounds__(64) void k_scan(
    const float* __restrict__ Wf, const float* __restrict__ Wi,
    const float* __restrict__ Wg, const float* __restrict__ Wo,
    const float* __restrict__ px2, float* __restrict__ hout)
{
    const int c = blockIdx.x * 64 + threadIdx.x;    // output row id 0..8191
    float wh[4][4][4];           // [gate][q][j]  (wave-uniform -> SGPRs)
    {
        const float* Ws[4] = {Wf, Wi, Wg, Wo};
#pragma unroll
        for (int g = 0; g < 4; ++g)
#pragma unroll
            for (int q = 0; q < 4; ++q)
#pragma unroll
                for (int j = 0; j < 4; ++j)
                    wh[g][q][j] = Ws[g][q * DSTRIDE + FEAT + j];
    }
    float h[4] = {0.f, 0.f, 0.f, 0.f};
    float cc[4] = {0.f, 0.f, 0.f, 0.f};

    float4 PN0, PN1, PN2, PN3;
    {
        const int n0 = c * LCH - WARM;
        const int nc = n0 < 0 ? 0 : n0;
        const float* p = px2 + (size_t)nc * 16;
        PN0 = *(const float4*)(p + 0);
        PN1 = *(const float4*)(p + 4);
        PN2 = *(const float4*)(p + 8);
        PN3 = *(const float4*)(p + 12);
    }

    for (int s = 0; s < STEPS; ++s) {
        const int n = c * LCH + s - WARM;

        float4 PP[4];
        PP[0] = PN0; PP[1] = PN1; PP[2] = PN2; PP[3] = PN3;

        {   // issue next-step loads now; they retire under this step's math
            int n2 = n + 1;
            n2 = n2 < 0 ? 0 : n2;
            n2 = n2 > (NN - 1) ? (NN - 1) : n2;
            const float* p2 = px2 + (size_t)n2 * 16;
            PN0 = *(const float4*)(p2 + 0);
            PN1 = *(const float4*)(p2 + 4);
            PN2 = *(const float4*)(p2 + 8);
            PN3 = *(const float4*)(p2 + 12);
        }

        float act[4][4];
#pragma unroll
        for (int g = 0; g < 4; ++g) {
            float z0 = PP[g].x, z1 = PP[g].y, z2 = PP[g].z, z3 = PP[g].w;
#pragma unroll
            for (int j = 0; j < 4; ++j) {
                z0 = fmaf(h[j], wh[g][0][j], z0);
                z1 = fmaf(h[j], wh[g][1][j], z1);
                z2 = fmaf(h[j], wh[g][2][j], z2);
                z3 = fmaf(h[j], wh[g][3][j], z3);
            }
            const float c0 = __cosf(z0), c1 = __cosf(z1);
            const float c2 = __cosf(z2), c3 = __cosf(z3);
            const float m01 = c0 * c1, t23 = c2 * c3;
            const float y0 = c1 * t23, y1 = m01, y2 = m01 * c2, y3 = m01 * t23;
            if (g == 2) {
                act[g][0] = tanh_f(y0); act[g][1] = tanh_f(y1);
                act[g][2] = tanh_f(y2); act[g][3] = tanh_f(y3);
            } else {
                act[g][0] = sigm_f(y0); act[g][1] = sigm_f(y1);
                act[g][2] = sigm_f(y2); act[g][3] = sigm_f(y3);
            }
        }
        if (n >= 0) {
#pragma unroll
            for (int q = 0; q < 4; ++q) {
                const float cn = fmaf(act[0][q], cc[q], act[1][q] * act[2][q]);
                cc[q] = cn;
                h[q] = act[3][q] * tanh_f(cn);
            }
        }
        if (s >= WARM) {
            *(float4*)(hout + (size_t)n * 4) = make_float4(h[0], h[1], h[2], h[3]);
        }
    }
}

// ---------------------------------------------------------------------------
// K3a: rows 0..8175, 8 rows per block (1022 blocks). Wfin fragment (8 rows x
// 16B) loaded into registers ONCE and reused across all 8 n-rows.
// Never writes the hout region (rows 8176..8191). ~64MB write floor ~10.5us.
// ---------------------------------------------------------------------------
__global__ __launch_bounds__(256) void k_out_main(
    const float* __restrict__ hout,
    const float* __restrict__ Wfin, const float* __restrict__ bfin,
    float* __restrict__ out)
{
    const int n0 = blockIdx.x * 8;
    const int ko = threadIdx.x * 8;
    float4 w[8];
#pragma unroll
    for (int j = 0; j < 8; ++j)
        w[j] = *(const float4*)(Wfin + (size_t)(ko + j) * 4);
    const float4 b0 = *(const float4*)(bfin + ko);
    const float4 b1 = *(const float4*)(bfin + ko + 4);
    const float bb[8] = {b0.x, b0.y, b0.z, b0.w, b1.x, b1.y, b1.z, b1.w};

#pragma unroll
    for (int r = 0; r < 8; ++r) {
        const int n = n0 + r;
        const float4 h = *(const float4*)(hout + (size_t)n * 4);
        float o[8];
#pragma unroll
        for (int j = 0; j < 8; ++j) {
            float v = bb[j];
            v = fmaf(h.x, w[j].x, v); v = fmaf(h.y, w[j].y, v);
            v = fmaf(h.z, w[j].z, v); v = fmaf(h.w, w[j].w, v);
            o[j] = v;
        }
        float* dst = out + (size_t)n * 2048 + ko;
        *(float4*)(dst)     = make_float4(o[0], o[1], o[2], o[3]);
        *(float4*)(dst + 4) = make_float4(o[4], o[5], o[6], o[7]);
    }
}

// ---------------------------------------------------------------------------
// K3b: rows 8176..8191 (bytes hold hout). Stage 16 h-vectors in LDS, barrier,
// overwrite. 16 threads/row x 128 cols.
// ---------------------------------------------------------------------------
__global__ __launch_bounds__(256) void k_out_tail(
    const float* __restrict__ hout,
    const float* __restrict__ Wfin, const float* __restrict__ bfin,
    float* __restrict__ out)
{
    __shared__ float hs[16 * 4];
    const int t = threadIdx.x;
    if (t < 64) hs[t] = hout[(size_t)8176 * 4 + t];
    __syncthreads();
    const int r = t >> 4;
    const int n = 8176 + r;
    const int c0 = (t & 15) * 128;
    const float4 h = *(const float4*)(&hs[r * 4]);
    for (int j = 0; j < 128; j += 8) {
        const int ko = c0 + j;
        const float4 b0 = *(const float4*)(bfin + ko);
        const float4 b1 = *(const float4*)(bfin + ko + 4);
        const float bb[8] = {b0.x, b0.y, b0.z, b0.w, b1.x, b1.y, b1.z, b1.w};
        float o[8];
#pragma unroll
        for (int jj = 0; jj < 8; ++jj) {
            const float4 w = *(const float4*)(Wfin + (size_t)(ko + jj) * 4);
            float v = bb[jj];
            v = fmaf(h.x, w.x, v); v = fmaf(h.y, w.y, v);
            v = fmaf(h.z, w.z, v); v = fmaf(h.w, w.w, v);
            o[jj] = v;
        }
        float* dst = out + (size_t)n * 2048 + ko;
        *(float4*)(dst)     = make_float4(o[0], o[1], o[2], o[3]);
        *(float4*)(dst + 4) = make_float4(o[4], o[5], o[6], o[7]);
    }
}

__global__ __launch_bounds__(256) void k_sentinel(float* __restrict__ out) {
    const size_t i = (size_t)blockIdx.x * 256 + threadIdx.x;
    *(float4*)(out + i * 4) = make_float4(123.f, 123.f, 123.f, 123.f);
}

extern "C" void kernel_launch(void* const* d_in, const int* in_sizes, int n_in,
                              void* d_out, int out_size, void* d_ws, size_t ws_size,
                              hipStream_t stream)
{
    const float* feat = (const float*)d_in[0];
    const float* Wf   = (const float*)d_in[1];
    const float* bfp  = (const float*)d_in[2];
    const float* Wi   = (const float*)d_in[3];
    const float* bip  = (const float*)d_in[4];
    const float* Wg   = (const float*)d_in[5];
    const float* bgp  = (const float*)d_in[6];
    const float* Wo   = (const float*)d_in[7];
    const float* bop  = (const float*)d_in[8];
    const float* thf  = (const float*)d_in[9];
    const float* thi  = (const float*)d_in[10];
    const float* thg  = (const float*)d_in[11];
    const float* tho  = (const float*)d_in[12];
    const float* Wfin = (const float*)d_in[13];
    const float* bfin = (const float*)d_in[14];

    bool ok = (n_in == 15) &&
              in_sizes[0] == 8192 * 2048 &&
              in_sizes[1] == 8208 && in_sizes[3] == 8208 &&
              in_sizes[5] == 8208 && in_sizes[7] == 8208 &&
              in_sizes[2] == 4 && in_sizes[4] == 4 &&
              in_sizes[6] == 4 && in_sizes[8] == 4 &&
              in_sizes[9] == 4 && in_sizes[10] == 4 &&
              in_sizes[11] == 4 && in_sizes[12] == 4 &&
              in_sizes[13] == 8192 && in_sizes[14] == 2048 &&
              out_size == 8192 * 2048;
    if (!ok) {
        hipLaunchKernelGGL(k_sentinel, dim3(8192 * 2048 / 1024), dim3(256), 0,
                           stream, (float*)d_out);
        return;
    }

    // F32 output = 64 MB. Zero workspace: px2 = head 512 KB (rows 0..63),
    // hout = tail 128 KB (rows 8176..8191). Consumers ordered on `stream`.
    char* ob = (char*)d_out;
    float* px2  = (float*)ob;
    float* hout = (float*)(ob + (size_t)NN * 2048 * 4 - (size_t)NN * 16);
    float* out  = (float*)d_out;

    hipLaunchKernelGGL(k_px, dim3(NN / PXROWS), dim3(256), 0, stream,
                       feat, Wf, Wi, Wg, Wo, bfp, bip, bgp, bop,
                       thf, thi, thg, tho, px2);
    hipLaunchKernelGGL(k_scan, dim3(128), dim3(64), 0, stream,
                       Wf, Wi, Wg, Wo, px2, hout);
    hipLaunchKernelGGL(k_out_main, dim3(1022), dim3(256), 0, stream,
                       hout, Wfin, bfin, out);
    hipLaunchKernelGGL(k_out_tail, dim3(1), dim3(256), 0, stream,
                       hout, Wfin, bfin, out);
}

// Round 10
// 228.808 us; speedup vs baseline: 1.3761x; 1.3761x over previous
//
#include <hip/hip_runtime.h>
#include <stdint.h>
#include <math.h>

typedef unsigned int uint_t;

#define FEAT 2048
#define DSTRIDE 2052   // FEAT + HIDDEN
#define WARM 40
#define LCH 1
#define STEPS (WARM + LCH)
#define NN 8192
#define PXROWS 8       // rows per k_px block (1024 blocks, 4-5/CU)

__device__ __forceinline__ float sigm_f(float x) {
    return __builtin_amdgcn_rcpf(1.f + __expf(-x));
}
__device__ __forceinline__ float tanh_f(float x) {
    // 1 - 2/(e^2x + 1); rcp is ~1 ulp, fine at 1e-2 threshold
    return 1.f - 2.f * __builtin_amdgcn_rcpf(__expf(2.f * x) + 1.f);
}

// ---------------------------------------------------------------------------
// K1 (f32 inputs): px2[n][gq] = feat[n,:]·Wx[gq,:2048] + b[gq] + th[gq]
// v8 = v4b (proven 40us, 44 VGPR, 0 conflicts) + feat-only prefetch.
// Pipeline history: v5 hoist-all = barrier drain + VGPR 112 (52us); v6 W-reg
// double-buffer = spill 80MB (65us); v7 no-LDS full-unroll = VGPR 256, spill
// 118MB (133us). Lesson: only modest structure + low VGPR wins on this
// compiler. v8 changes ONE thing vs v4b: the next chunk's 4 feat float4
// loads (HBM ~900cy) are issued right after the "Wl ready" barrier, so they
// retire under compute(ch) (~500cy) + W-staging (~500cy) instead of being
// drained cold at the next barrier. +16 VGPR only (fna/fnb); W staging keeps
// v4b's load->ds_write form with transient regs.
//   * conflict-free LDS mapping (v4b): lane*16B stride = 8x/bank minimum.
//   * FMA order identical to v4b -> px2 bit-identical -> absmax unchanged.
// px2 = 512 KB at head of d_out (f32 rows 0..63), consumed by k_scan before
// k_out_main overwrites it.
// ---------------------------------------------------------------------------
__global__ __launch_bounds__(256) void k_px(
    const float* __restrict__ feat,
    const float* __restrict__ Wf, const float* __restrict__ Wi,
    const float* __restrict__ Wg, const float* __restrict__ Wo,
    const float* __restrict__ bfp, const float* __restrict__ bip,
    const float* __restrict__ bgp, const float* __restrict__ bop,
    const float* __restrict__ thf, const float* __restrict__ thi,
    const float* __restrict__ thg, const float* __restrict__ tho,
    float* __restrict__ px2)
{
    __shared__ float Wl[16 * 512];   // one 512-float K-chunk of all 16 gq rows
    const int t = threadIdx.x;
    const int wave = t >> 6, lane = t & 63;
    const int rowBase = blockIdx.x * PXROWS;
    const float* Ws[4] = {Wf, Wi, Wg, Wo};

    // ---- prologue: stage W chunk 0; issue feat chunk 0 loads ----
    for (int i4 = t; i4 < 2048; i4 += 256) {
        const int gq = i4 >> 7;
        const int jj = (i4 & 127) << 2;
        const float4 v = *(const float4*)(Ws[gq >> 2] + (gq & 3) * DSTRIDE + jj);
        *(float4*)(&Wl[gq * 512 + jj]) = v;
    }
    float4 fa[2], fb[2];
#pragma unroll
    for (int rr = 0; rr < 2; ++rr) {
        const int n = rowBase + wave * 2 + rr;
        const float* fp = feat + (size_t)n * FEAT;
        fa[rr] = *(const float4*)(fp + lane * 4);
        fb[rr] = *(const float4*)(fp + 256 + lane * 4);
    }

    float acc[2][16];
#pragma unroll
    for (int r = 0; r < 2; ++r)
#pragma unroll
        for (int i = 0; i < 16; ++i) acc[r][i] = 0.f;

    __syncthreads();   // Wl[0] ready

#pragma unroll
    for (int ch = 0; ch < 4; ++ch) {
        // issue next-chunk feat loads NOW; they retire under compute(ch)
        // and the W[ch+1] staging phase before first use in compute(ch+1).
        float4 fna[2], fnb[2];
        if (ch < 3) {
#pragma unroll
            for (int rr = 0; rr < 2; ++rr) {
                const int n = rowBase + wave * 2 + rr;
                const float* fp = feat + (size_t)n * FEAT + (ch + 1) * 512;
                fna[rr] = *(const float4*)(fp + lane * 4);
                fnb[rr] = *(const float4*)(fp + 256 + lane * 4);
            }
        }

        // compute(ch) — identical FMA order to v4b
#pragma unroll
        for (int gq = 0; gq < 16; ++gq) {
            const float4 wa = *(const float4*)(&Wl[gq * 512 + lane * 4]);
            const float4 wb = *(const float4*)(&Wl[gq * 512 + 256 + lane * 4]);
#pragma unroll
            for (int rr = 0; rr < 2; ++rr) {
                float a = acc[rr][gq];
                a = fmaf(fa[rr].x, wa.x, a); a = fmaf(fa[rr].y, wa.y, a);
                a = fmaf(fa[rr].z, wa.z, a); a = fmaf(fa[rr].w, wa.w, a);
                a = fmaf(fb[rr].x, wb.x, a); a = fmaf(fb[rr].y, wb.y, a);
                a = fmaf(fb[rr].z, wb.z, a); a = fmaf(fb[rr].w, wb.w, a);
                acc[rr][gq] = a;
            }
        }
        __syncthreads();   // all waves done reading Wl[ch]

        if (ch < 3) {
            // stage W[ch+1] (v4b's proven transient-reg load->ds_write)
            for (int i4 = t; i4 < 2048; i4 += 256) {
                const int gq = i4 >> 7;
                const int jj = (i4 & 127) << 2;
                const float4 v = *(const float4*)(Ws[gq >> 2] + (gq & 3) * DSTRIDE + (ch + 1) * 512 + jj);
                *(float4*)(&Wl[gq * 512 + jj]) = v;
            }
#pragma unroll
            for (int rr = 0; rr < 2; ++rr) { fa[rr] = fna[rr]; fb[rr] = fnb[rr]; }
            __syncthreads();   // Wl[ch+1] ready
        }
    }

    float bth[16];
    {
        const float* bs[4] = {bfp, bip, bgp, bop};
        const float* ts[4] = {thf, thi, thg, tho};
#pragma unroll
        for (int g = 0; g < 4; ++g)
#pragma unroll
            for (int q = 0; q < 4; ++q)
                bth[g * 4 + q] = bs[g][q] + ts[g][q];
    }

#pragma unroll
    for (int rr = 0; rr < 2; ++rr) {
#pragma unroll
        for (int i = 0; i < 16; ++i) {
            float v = acc[rr][i];
#pragma unroll
            for (int m = 32; m > 0; m >>= 1) v += __shfl_xor(v, m, 64);
            acc[rr][i] = v + bth[i];
        }
        if (lane == 0) {
            const int n = rowBase + wave * 2 + rr;
            float* dst = px2 + (size_t)n * 16;
            *(float4*)(dst + 0)  = make_float4(acc[rr][0],  acc[rr][1],  acc[rr][2],  acc[rr][3]);
            *(float4*)(dst + 4)  = make_float4(acc[rr][4],  acc[rr][5],  acc[rr][6],  acc[rr][7]);
            *(float4*)(dst + 8)  = make_float4(acc[rr][8],  acc[rr][9],  acc[rr][10], acc[rr][11]);
            *(float4*)(dst + 12) = make_float4(acc[rr][12], acc[rr][13], acc[rr][14], acc[rr][15]);
        }
    }
}

// ---------------------------------------------------------------------------
// K2: per-row warmup replay. 8192 chunks of 1 row each; every thread replays
// the 40 preceding rows from (h,c)=(0,0) then emits its single row. 128
// blocks x 64 threads -> 128 CUs (R2 lesson: CUs, not waves/SIMD).
// Rows n<40 bit-exact via the n<0 no-update guard; adversarial warmup bound
// 0.84^40 ~ 9.4e-4 << 1.06e-2 threshold; absmax bit-identical across
// WARM 64->40 (transcendental-dominated).
// px2 prefetched one step ahead (state-independent addresses). px2 is
// L2-resident (512 KB).
// qlayer(z,th) = [c1c2c3, c0c1, c0c1c2, c0c1c2c3], c_w = cos(z_w + th_w)
// (theta pre-added by k_px). hout = LAST 128 KB of d_out (rows 8176..8191).
// ---------------------------------------------------------------------------
__global__ __launch_bounds__(64) void k_scan(
    const float* __restrict__ Wf, const float* __restrict__ Wi,
    const float* __restrict__ Wg, const float* __restrict__ Wo,
    const float* __restrict__ px2, float* __restrict__ hout)
{
    const int c = blockIdx.x * 64 + threadIdx.x;    // output row id 0..8191
    float wh[4][4][4];           // [gate][q][j]  (wave-uniform -> SGPRs)
    {
        const float* Ws[4] = {Wf, Wi, Wg, Wo};
#pragma unroll
        for (int g = 0; g < 4; ++g)
#pragma unroll
            for (int q = 0; q < 4; ++q)
#pragma unroll
                for (int j = 0; j < 4; ++j)
                    wh[g][q][j] = Ws[g][q * DSTRIDE + FEAT + j];
    }
    float h[4] = {0.f, 0.f, 0.f, 0.f};
    float cc[4] = {0.f, 0.f, 0.f, 0.f};

    float4 PN0, PN1, PN2, PN3;
    {
        const int n0 = c * LCH - WARM;
        const int nc = n0 < 0 ? 0 : n0;
        const float* p = px2 + (size_t)nc * 16;
        PN0 = *(const float4*)(p + 0);
        PN1 = *(const float4*)(p + 4);
        PN2 = *(const float4*)(p + 8);
        PN3 = *(const float4*)(p + 12);
    }

    for (int s = 0; s < STEPS; ++s) {
        const int n = c * LCH + s - WARM;

        float4 PP[4];
        PP[0] = PN0; PP[1] = PN1; PP[2] = PN2; PP[3] = PN3;

        {   // issue next-step loads now; they retire under this step's math
            int n2 = n + 1;
            n2 = n2 < 0 ? 0 : n2;
            n2 = n2 > (NN - 1) ? (NN - 1) : n2;
            const float* p2 = px2 + (size_t)n2 * 16;
            PN0 = *(const float4*)(p2 + 0);
            PN1 = *(const float4*)(p2 + 4);
            PN2 = *(const float4*)(p2 + 8);
            PN3 = *(const float4*)(p2 + 12);
        }

        float act[4][4];
#pragma unroll
        for (int g = 0; g < 4; ++g) {
            float z0 = PP[g].x, z1 = PP[g].y, z2 = PP[g].z, z3 = PP[g].w;
#pragma unroll
            for (int j = 0; j < 4; ++j) {
                z0 = fmaf(h[j], wh[g][0][j], z0);
                z1 = fmaf(h[j], wh[g][1][j], z1);
                z2 = fmaf(h[j], wh[g][2][j], z2);
                z3 = fmaf(h[j], wh[g][3][j], z3);
            }
            const float c0 = __cosf(z0), c1 = __cosf(z1);
            const float c2 = __cosf(z2), c3 = __cosf(z3);
            const float m01 = c0 * c1, t23 = c2 * c3;
            const float y0 = c1 * t23, y1 = m01, y2 = m01 * c2, y3 = m01 * t23;
            if (g == 2) {
                act[g][0] = tanh_f(y0); act[g][1] = tanh_f(y1);
                act[g][2] = tanh_f(y2); act[g][3] = tanh_f(y3);
            } else {
                act[g][0] = sigm_f(y0); act[g][1] = sigm_f(y1);
                act[g][2] = sigm_f(y2); act[g][3] = sigm_f(y3);
            }
        }
        if (n >= 0) {
#pragma unroll
            for (int q = 0; q < 4; ++q) {
                const float cn = fmaf(act[0][q], cc[q], act[1][q] * act[2][q]);
                cc[q] = cn;
                h[q] = act[3][q] * tanh_f(cn);
            }
        }
        if (s >= WARM) {
            *(float4*)(hout + (size_t)n * 4) = make_float4(h[0], h[1], h[2], h[3]);
        }
    }
}

// ---------------------------------------------------------------------------
// K3a: rows 0..8175, 8 rows per block (1022 blocks). Wfin fragment (8 rows x
// 16B) loaded into registers ONCE and reused across all 8 n-rows.
// Never writes the hout region (rows 8176..8191). ~64MB write floor ~10.5us.
// ---------------------------------------------------------------------------
__global__ __launch_bounds__(256) void k_out_main(
    const float* __restrict__ hout,
    const float* __restrict__ Wfin, const float* __restrict__ bfin,
    float* __restrict__ out)
{
    const int n0 = blockIdx.x * 8;
    const int ko = threadIdx.x * 8;
    float4 w[8];
#pragma unroll
    for (int j = 0; j < 8; ++j)
        w[j] = *(const float4*)(Wfin + (size_t)(ko + j) * 4);
    const float4 b0 = *(const float4*)(bfin + ko);
    const float4 b1 = *(const float4*)(bfin + ko + 4);
    const float bb[8] = {b0.x, b0.y, b0.z, b0.w, b1.x, b1.y, b1.z, b1.w};

#pragma unroll
    for (int r = 0; r < 8; ++r) {
        const int n = n0 + r;
        const float4 h = *(const float4*)(hout + (size_t)n * 4);
        float o[8];
#pragma unroll
        for (int j = 0; j < 8; ++j) {
            float v = bb[j];
            v = fmaf(h.x, w[j].x, v); v = fmaf(h.y, w[j].y, v);
            v = fmaf(h.z, w[j].z, v); v = fmaf(h.w, w[j].w, v);
            o[j] = v;
        }
        float* dst = out + (size_t)n * 2048 + ko;
        *(float4*)(dst)     = make_float4(o[0], o[1], o[2], o[3]);
        *(float4*)(dst + 4) = make_float4(o[4], o[5], o[6], o[7]);
    }
}

// ---------------------------------------------------------------------------
// K3b: rows 8176..8191 (bytes hold hout). Stage 16 h-vectors in LDS, barrier,
// overwrite. 16 threads/row x 128 cols.
// ---------------------------------------------------------------------------
__global__ __launch_bounds__(256) void k_out_tail(
    const float* __restrict__ hout,
    const float* __restrict__ Wfin, const float* __restrict__ bfin,
    float* __restrict__ out)
{
    __shared__ float hs[16 * 4];
    const int t = threadIdx.x;
    if (t < 64) hs[t] = hout[(size_t)8176 * 4 + t];
    __syncthreads();
    const int r = t >> 4;
    const int n = 8176 + r;
    const int c0 = (t & 15) * 128;
    const float4 h = *(const float4*)(&hs[r * 4]);
    for (int j = 0; j < 128; j += 8) {
        const int ko = c0 + j;
        const float4 b0 = *(const float4*)(bfin + ko);
        const float4 b1 = *(const float4*)(bfin + ko + 4);
        const float bb[8] = {b0.x, b0.y, b0.z, b0.w, b1.x, b1.y, b1.z, b1.w};
        float o[8];
#pragma unroll
        for (int jj = 0; jj < 8; ++jj) {
            const float4 w = *(const float4*)(Wfin + (size_t)(ko + jj) * 4);
            float v = bb[jj];
            v = fmaf(h.x, w.x, v); v = fmaf(h.y, w.y, v);
            v = fmaf(h.z, w.z, v); v = fmaf(h.w, w.w, v);
            o[jj] = v;
        }
        float* dst = out + (size_t)n * 2048 + ko;
        *(float4*)(dst)     = make_float4(o[0], o[1], o[2], o[3]);
        *(float4*)(dst + 4) = make_float4(o[4], o[5], o[6], o[7]);
    }
}

__global__ __launch_bounds__(256) void k_sentinel(float* __restrict__ out) {
    const size_t i = (size_t)blockIdx.x * 256 + threadIdx.x;
    *(float4*)(out + i * 4) = make_float4(123.f, 123.f, 123.f, 123.f);
}

extern "C" void kernel_launch(void* const* d_in, const int* in_sizes, int n_in,
                              void* d_out, int out_size, void* d_ws, size_t ws_size,
                              hipStream_t stream)
{
    const float* feat = (const float*)d_in[0];
    const float* Wf   = (const float*)d_in[1];
    const float* bfp  = (const float*)d_in[2];
    const float* Wi   = (const float*)d_in[3];
    const float* bip  = (const float*)d_in[4];
    const float* Wg   = (const float*)d_in[5];
    const float* bgp  = (const float*)d_in[6];
    const float* Wo   = (const float*)d_in[7];
    const float* bop  = (const float*)d_in[8];
    const float* thf  = (const float*)d_in[9];
    const float* thi  = (const float*)d_in[10];
    const float* thg  = (const float*)d_in[11];
    const float* tho  = (const float*)d_in[12];
    const float* Wfin = (const float*)d_in[13];
    const float* bfin = (const float*)d_in[14];

    bool ok = (n_in == 15) &&
              in_sizes[0] == 8192 * 2048 &&
              in_sizes[1] == 8208 && in_sizes[3] == 8208 &&
              in_sizes[5] == 8208 && in_sizes[7] == 8208 &&
              in_sizes[2] == 4 && in_sizes[4] == 4 &&
              in_sizes[6] == 4 && in_sizes[8] == 4 &&
              in_sizes[9] == 4 && in_sizes[10] == 4 &&
              in_sizes[11] == 4 && in_sizes[12] == 4 &&
              in_sizes[13] == 8192 && in_sizes[14] == 2048 &&
              out_size == 8192 * 2048;
    if (!ok) {
        hipLaunchKernelGGL(k_sentinel, dim3(8192 * 2048 / 1024), dim3(256), 0,
                           stream, (float*)d_out);
        return;
    }

    // F32 output = 64 MB. Zero workspace: px2 = head 512 KB (rows 0..63),
    // hout = tail 128 KB (rows 8176..8191). Consumers ordered on `stream`.
    char* ob = (char*)d_out;
    float* px2  = (float*)ob;
    float* hout = (float*)(ob + (size_t)NN * 2048 * 4 - (size_t)NN * 16);
    float* out  = (float*)d_out;

    hipLaunchKernelGGL(k_px, dim3(NN / PXROWS), dim3(256), 0, stream,
                       feat, Wf, Wi, Wg, Wo, bfp, bip, bgp, bop,
                       thf, thi, thg, tho, px2);
    hipLaunchKernelGGL(k_scan, dim3(128), dim3(64), 0, stream,
                       Wf, Wi, Wg, Wo, px2, hout);
    hipLaunchKernelGGL(k_out_main, dim3(1022), dim3(256), 0, stream,
                       hout, Wfin, bfin, out);
    hipLaunchKernelGGL(k_out_tail, dim3(1), dim3(256), 0, stream,
                       hout, Wfin, bfin, out);
}

// Round 11
// 210.250 us; speedup vs baseline: 1.4975x; 1.0883x over previous
//
#include <hip/hip_runtime.h>
#include <stdint.h>
#include <math.h>

typedef unsigned int uint_t;
typedef __attribute__((ext_vector_type(8))) short bf16x8;   // 8 bf16 (4 VGPRs)
typedef __attribute__((ext_vector_type(4))) float f32x4;

#define FEAT 2048
#define DSTRIDE 2052   // FEAT + HIDDEN
#define WARM 40
#define LCH 1
#define STEPS (WARM + LCH)
#define NN 8192
#define NSL 8          // K-slices for k_px split-K
#define KS 256         // K per slice (NSL*KS = FEAT)
#define MBLK 64        // rows per k_px block (4 waves x 16)
#define WSTR (KS + 8)  // LDS stride in shorts; byte stride 528 = 33*16 (aligned, conflict-spread)

__device__ __forceinline__ float sigm_f(float x) {
    return __builtin_amdgcn_rcpf(1.f + __expf(-x));
}
__device__ __forceinline__ float tanh_f(float x) {
    // 1 - 2/(e^2x + 1); rcp is ~1 ulp, fine at 1e-2 threshold
    return 1.f - 2.f * __builtin_amdgcn_rcpf(__expf(2.f * x) + 1.f);
}
__device__ __forceinline__ short bf16rne(float x) {
    uint32_t u = __float_as_uint(x);
    u += 0x7FFFu + ((u >> 16) & 1u);   // round-to-nearest-even
    return (short)(u >> 16);
}

// ---------------------------------------------------------------------------
// K1 v9: MFMA split-K GEMM. px2p[s][n][gq] = feat[n, s*256:(s+1)*256]·W[gq,·]
// R10 verdict: the scalar-FMA/LDS/barrier structure is floored at ~40us
// (v4b=40, v5=52, v6=65, v7=133, v8=44 — every pipelining variant drains at
// a barrier, spills, or loses occupancy). This IS a GEMM (8192x16x2048) —
// Guideline 10. mfma_f32_16x16x32_bf16 removes BOTH structural costs:
//   * the 64-lane shuffle reduce (K summed inside the matrix core);
//   * the 4-chunk barrier ladder (W-slice staged ONCE as bf16, 8.4KB LDS,
//     one barrier, then a barrier-free 8-MFMA loop).
// Fragment maps: A=feat tile (row=l&15, k=(l>>4)*8+i), B=W (col=l&15 -> gq,
// same k map). Any bijective k-map shared by A and B is correct (HW pairs
// same-slot elements); C/D map is HW-verified (m89): col=lane&15,
// row=(lane>>4)*4+reg. bf16 RNE on inputs: z err ~5e-5 -> final ~<=1e-3.
// Grid 8 slices x 128 mgroups = 1024 blocks, 4 waves/SIMD. Full unroll
// hoists 16 float4 A-loads (~64 VGPR — safe scale; v7's spill was 128).
// px2p = 4MB at d_out head after px2 (rows 64..575), consumed by k_red.
// ---------------------------------------------------------------------------
__global__ __launch_bounds__(256) void k_px(
    const float* __restrict__ feat,
    const float* __restrict__ Wf, const float* __restrict__ Wi,
    const float* __restrict__ Wg, const float* __restrict__ Wo,
    float* __restrict__ px2p)
{
    __shared__ short WT[16 * WSTR];   // bf16 W-slice, 16 gq x 256 k
    const int t = threadIdx.x;
    const int slice = blockIdx.x >> 7;    // 0..7
    const int mg = blockIdx.x & 127;      // 0..127
    const int kb = slice * KS;
    const float* Ws[4] = {Wf, Wi, Wg, Wo};

    // stage W slice as bf16: 16 x 256 = 1024 float4-groups, 4 per thread
    for (int i4 = t; i4 < 1024; i4 += 256) {
        const int gq = i4 >> 6;
        const int jj = (i4 & 63) << 2;
        const float4 v = *(const float4*)(Ws[gq >> 2] + (gq & 3) * DSTRIDE + kb + jj);
        short4 h;
        h.x = bf16rne(v.x); h.y = bf16rne(v.y);
        h.z = bf16rne(v.z); h.w = bf16rne(v.w);
        *(short4*)(&WT[gq * WSTR + jj]) = h;
    }
    __syncthreads();   // the ONLY barrier

    const int wv = t >> 6, l = t & 63;
    const int row0 = mg * MBLK + wv * 16;
    const int m  = l & 15;       // A row within tile / B col (gq)
    const int kg = l >> 4;       // k-group 0..3
    const float* fp = feat + (size_t)(row0 + m) * FEAT + kb + kg * 8;
    const short* bp = &WT[m * WSTR + kg * 8];

    f32x4 acc = {0.f, 0.f, 0.f, 0.f};
#pragma unroll
    for (int ks = 0; ks < KS / 32; ++ks) {   // 8 chained MFMAs
        const float4 a0 = *(const float4*)(fp + ks * 32);
        const float4 a1 = *(const float4*)(fp + ks * 32 + 4);
        bf16x8 af;
        af[0] = bf16rne(a0.x); af[1] = bf16rne(a0.y);
        af[2] = bf16rne(a0.z); af[3] = bf16rne(a0.w);
        af[4] = bf16rne(a1.x); af[5] = bf16rne(a1.y);
        af[6] = bf16rne(a1.z); af[7] = bf16rne(a1.w);
        const bf16x8 bfr = *(const bf16x8*)(bp + ks * 32);
        acc = __builtin_amdgcn_mfma_f32_16x16x32_bf16(af, bfr, acc, 0, 0, 0);
    }

    // D: col = lane&15 (gq), row = (lane>>4)*4 + r  [HW-verified m89]
#pragma unroll
    for (int r = 0; r < 4; ++r) {
        const int row = row0 + kg * 4 + r;
        px2p[((size_t)slice * NN + row) * 16 + m] = acc[r];
    }
}

// ---------------------------------------------------------------------------
// K1b: reduce 8 slice-partials + add (b + theta). 128 blocks x 256 threads;
// thread i handles float4 i: n = i>>2, gate g = i&3 (4 consecutive gq).
// Reads 4MB (L2-resident), writes px2 512KB. Deterministic fixed-order sum.
// ---------------------------------------------------------------------------
__global__ __launch_bounds__(256) void k_red(
    const float4* __restrict__ px2p,
    const float* __restrict__ bfp, const float* __restrict__ bip,
    const float* __restrict__ bgp, const float* __restrict__ bop,
    const float* __restrict__ thf, const float* __restrict__ thi,
    const float* __restrict__ thg, const float* __restrict__ tho,
    float4* __restrict__ px2)
{
    const int i = blockIdx.x * 256 + threadIdx.x;   // 0..32767
    float4 s = px2p[i];
#pragma unroll
    for (int sl = 1; sl < NSL; ++sl) {
        const float4 v = px2p[(size_t)sl * 32768 + i];
        s.x += v.x; s.y += v.y; s.z += v.z; s.w += v.w;
    }
    const int g = i & 3;
    const float* bs[4] = {bfp, bip, bgp, bop};
    const float* ts[4] = {thf, thi, thg, tho};
    const float4 b  = *(const float4*)(bs[g]);
    const float4 th = *(const float4*)(ts[g]);
    s.x += b.x + th.x; s.y += b.y + th.y;
    s.z += b.z + th.z; s.w += b.w + th.w;
    px2[i] = s;
}

// ---------------------------------------------------------------------------
// K2: per-row warmup replay (UNCHANGED from R5-proven version). 8192 chunks
// of 1 row; 128 blocks x 64 threads -> 128 CUs. Rows n<40 bit-exact via the
// n<0 no-update guard; adversarial warmup bound 0.84^40 ~ 9.4e-4 << 1e-2.
// px2 prefetched one step ahead. qlayer(z,th) = [c1c2c3, c0c1, c0c1c2,
// c0c1c2c3], c_w = cos(z_w + th_w) (theta pre-added by k_red).
// hout = LAST 128 KB of d_out (rows 8176..8191).
// ---------------------------------------------------------------------------
__global__ __launch_bounds__(64) void k_scan(
    const float* __restrict__ Wf, const float* __restrict__ Wi,
    const float* __restrict__ Wg, const float* __restrict__ Wo,
    const float* __restrict__ px2, float* __restrict__ hout)
{
    const int c = blockIdx.x * 64 + threadIdx.x;    // output row id 0..8191
    float wh[4][4][4];           // [gate][q][j]  (wave-uniform -> SGPRs)
    {
        const float* Ws[4] = {Wf, Wi, Wg, Wo};
#pragma unroll
        for (int g = 0; g < 4; ++g)
#pragma unroll
            for (int q = 0; q < 4; ++q)
#pragma unroll
                for (int j = 0; j < 4; ++j)
                    wh[g][q][j] = Ws[g][q * DSTRIDE + FEAT + j];
    }
    float h[4] = {0.f, 0.f, 0.f, 0.f};
    float cc[4] = {0.f, 0.f, 0.f, 0.f};

    float4 PN0, PN1, PN2, PN3;
    {
        const int n0 = c * LCH - WARM;
        const int nc = n0 < 0 ? 0 : n0;
        const float* p = px2 + (size_t)nc * 16;
        PN0 = *(const float4*)(p + 0);
        PN1 = *(const float4*)(p + 4);
        PN2 = *(const float4*)(p + 8);
        PN3 = *(const float4*)(p + 12);
    }

    for (int s = 0; s < STEPS; ++s) {
        const int n = c * LCH + s - WARM;

        float4 PP[4];
        PP[0] = PN0; PP[1] = PN1; PP[2] = PN2; PP[3] = PN3;

        {   // issue next-step loads now; they retire under this step's math
            int n2 = n + 1;
            n2 = n2 < 0 ? 0 : n2;
            n2 = n2 > (NN - 1) ? (NN - 1) : n2;
            const float* p2 = px2 + (size_t)n2 * 16;
            PN0 = *(const float4*)(p2 + 0);
            PN1 = *(const float4*)(p2 + 4);
            PN2 = *(const float4*)(p2 + 8);
            PN3 = *(const float4*)(p2 + 12);
        }

        float act[4][4];
#pragma unroll
        for (int g = 0; g < 4; ++g) {
            float z0 = PP[g].x, z1 = PP[g].y, z2 = PP[g].z, z3 = PP[g].w;
#pragma unroll
            for (int j = 0; j < 4; ++j) {
                z0 = fmaf(h[j], wh[g][0][j], z0);
                z1 = fmaf(h[j], wh[g][1][j], z1);
                z2 = fmaf(h[j], wh[g][2][j], z2);
                z3 = fmaf(h[j], wh[g][3][j], z3);
            }
            const float c0 = __cosf(z0), c1 = __cosf(z1);
            const float c2 = __cosf(z2), c3 = __cosf(z3);
            const float m01 = c0 * c1, t23 = c2 * c3;
            const float y0 = c1 * t23, y1 = m01, y2 = m01 * c2, y3 = m01 * t23;
            if (g == 2) {
                act[g][0] = tanh_f(y0); act[g][1] = tanh_f(y1);
                act[g][2] = tanh_f(y2); act[g][3] = tanh_f(y3);
            } else {
                act[g][0] = sigm_f(y0); act[g][1] = sigm_f(y1);
                act[g][2] = sigm_f(y2); act[g][3] = sigm_f(y3);
            }
        }
        if (n >= 0) {
#pragma unroll
            for (int q = 0; q < 4; ++q) {
                const float cn = fmaf(act[0][q], cc[q], act[1][q] * act[2][q]);
                cc[q] = cn;
                h[q] = act[3][q] * tanh_f(cn);
            }
        }
        if (s >= WARM) {
            *(float4*)(hout + (size_t)n * 4) = make_float4(h[0], h[1], h[2], h[3]);
        }
    }
}

// ---------------------------------------------------------------------------
// K3a: rows 0..8175, 8 rows per block (1022 blocks). Wfin fragment (8 rows x
// 16B) loaded into registers ONCE and reused across all 8 n-rows.
// Never writes the hout region (rows 8176..8191). ~64MB write floor ~10.5us.
// ---------------------------------------------------------------------------
__global__ __launch_bounds__(256) void k_out_main(
    const float* __restrict__ hout,
    const float* __restrict__ Wfin, const float* __restrict__ bfin,
    float* __restrict__ out)
{
    const int n0 = blockIdx.x * 8;
    const int ko = threadIdx.x * 8;
    float4 w[8];
#pragma unroll
    for (int j = 0; j < 8; ++j)
        w[j] = *(const float4*)(Wfin + (size_t)(ko + j) * 4);
    const float4 b0 = *(const float4*)(bfin + ko);
    const float4 b1 = *(const float4*)(bfin + ko + 4);
    const float bb[8] = {b0.x, b0.y, b0.z, b0.w, b1.x, b1.y, b1.z, b1.w};

#pragma unroll
    for (int r = 0; r < 8; ++r) {
        const int n = n0 + r;
        const float4 h = *(const float4*)(hout + (size_t)n * 4);
        float o[8];
#pragma unroll
        for (int j = 0; j < 8; ++j) {
            float v = bb[j];
            v = fmaf(h.x, w[j].x, v); v = fmaf(h.y, w[j].y, v);
            v = fmaf(h.z, w[j].z, v); v = fmaf(h.w, w[j].w, v);
            o[j] = v;
        }
        float* dst = out + (size_t)n * 2048 + ko;
        *(float4*)(dst)     = make_float4(o[0], o[1], o[2], o[3]);
        *(float4*)(dst + 4) = make_float4(o[4], o[5], o[6], o[7]);
    }
}

// ---------------------------------------------------------------------------
// K3b: rows 8176..8191 (bytes hold hout). Stage 16 h-vectors in LDS, barrier,
// overwrite. 16 threads/row x 128 cols.
// ---------------------------------------------------------------------------
__global__ __launch_bounds__(256) void k_out_tail(
    const float* __restrict__ hout,
    const float* __restrict__ Wfin, const float* __restrict__ bfin,
    float* __restrict__ out)
{
    __shared__ float hs[16 * 4];
    const int t = threadIdx.x;
    if (t < 64) hs[t] = hout[(size_t)8176 * 4 + t];
    __syncthreads();
    const int r = t >> 4;
    const int n = 8176 + r;
    const int c0 = (t & 15) * 128;
    const float4 h = *(const float4*)(&hs[r * 4]);
    for (int j = 0; j < 128; j += 8) {
        const int ko = c0 + j;
        const float4 b0 = *(const float4*)(bfin + ko);
        const float4 b1 = *(const float4*)(bfin + ko + 4);
        const float bb[8] = {b0.x, b0.y, b0.z, b0.w, b1.x, b1.y, b1.z, b1.w};
        float o[8];
#pragma unroll
        for (int jj = 0; jj < 8; ++jj) {
            const float4 w = *(const float4*)(Wfin + (size_t)(ko + jj) * 4);
            float v = bb[jj];
            v = fmaf(h.x, w.x, v); v = fmaf(h.y, w.y, v);
            v = fmaf(h.z, w.z, v); v = fmaf(h.w, w.w, v);
            o[jj] = v;
        }
        float* dst = out + (size_t)n * 2048 + ko;
        *(float4*)(dst)     = make_float4(o[0], o[1], o[2], o[3]);
        *(float4*)(dst + 4) = make_float4(o[4], o[5], o[6], o[7]);
    }
}

__global__ __launch_bounds__(256) void k_sentinel(float* __restrict__ out) {
    const size_t i = (size_t)blockIdx.x * 256 + threadIdx.x;
    *(float4*)(out + i * 4) = make_float4(123.f, 123.f, 123.f, 123.f);
}

extern "C" void kernel_launch(void* const* d_in, const int* in_sizes, int n_in,
                              void* d_out, int out_size, void* d_ws, size_t ws_size,
                              hipStream_t stream)
{
    const float* feat = (const float*)d_in[0];
    const float* Wf   = (const float*)d_in[1];
    const float* bfp  = (const float*)d_in[2];
    const float* Wi   = (const float*)d_in[3];
    const float* bip  = (const float*)d_in[4];
    const float* Wg   = (const float*)d_in[5];
    const float* bgp  = (const float*)d_in[6];
    const float* Wo   = (const float*)d_in[7];
    const float* bop  = (const float*)d_in[8];
    const float* thf  = (const float*)d_in[9];
    const float* thi  = (const float*)d_in[10];
    const float* thg  = (const float*)d_in[11];
    const float* tho  = (const float*)d_in[12];
    const float* Wfin = (const float*)d_in[13];
    const float* bfin = (const float*)d_in[14];

    bool ok = (n_in == 15) &&
              in_sizes[0] == 8192 * 2048 &&
              in_sizes[1] == 8208 && in_sizes[3] == 8208 &&
              in_sizes[5] == 8208 && in_sizes[7] == 8208 &&
              in_sizes[2] == 4 && in_sizes[4] == 4 &&
              in_sizes[6] == 4 && in_sizes[8] == 4 &&
              in_sizes[9] == 4 && in_sizes[10] == 4 &&
              in_sizes[11] == 4 && in_sizes[12] == 4 &&
              in_sizes[13] == 8192 && in_sizes[14] == 2048 &&
              out_size == 8192 * 2048;
    if (!ok) {
        hipLaunchKernelGGL(k_sentinel, dim3(8192 * 2048 / 1024), dim3(256), 0,
                           stream, (float*)d_out);
        return;
    }

    // Zero-workspace layout in d_out (64 MB f32):
    //   px2  = head 512 KB (out rows 0..63)      — final pre-activations
    //   px2p = next 4 MB  (out rows 64..575)     — 8 slice partials
    //   hout = tail 128 KB (out rows 8176..8191) — scan output
    // Order: k_px -> k_red -> k_scan -> k_out_{main,tail}; all on `stream`.
    char* ob = (char*)d_out;
    float* px2  = (float*)ob;
    float* px2p = (float*)(ob + (size_t)512 * 1024);
    float* hout = (float*)(ob + (size_t)NN * 2048 * 4 - (size_t)NN * 16);
    float* out  = (float*)d_out;

    hipLaunchKernelGGL(k_px, dim3(NSL * 128), dim3(256), 0, stream,
                       feat, Wf, Wi, Wg, Wo, px2p);
    hipLaunchKernelGGL(k_red, dim3(128), dim3(256), 0, stream,
                       (const float4*)px2p, bfp, bip, bgp, bop,
                       thf, thi, thg, tho, (float4*)px2);
    hipLaunchKernelGGL(k_scan, dim3(128), dim3(64), 0, stream,
                       Wf, Wi, Wg, Wo, px2, hout);
    hipLaunchKernelGGL(k_out_main, dim3(1022), dim3(256), 0, stream,
                       hout, Wfin, bfin, out);
    hipLaunchKernelGGL(k_out_tail, dim3(1), dim3(256), 0, stream,
                       hout, Wfin, bfin, out);
}